// Round 3
// baseline (115.821 us; speedup 1.0000x reference)
//
#include <hip/hip_runtime.h>
#include <math.h>

#define NB 16
#define NA 19200
#define NT 50
#define NC 80
#define LAMBDA_COORD 5.0f
#define F_EPS 1e-6f

#define NCHUNK 25
#define A_BLK  768              // NA / NCHUNK; 3 anchors per thread at 256 threads
#define TG     10               // targets per pass
#define NPASS  (NT / TG)        // 5

#define OBJ_CHUNKS (NA / 256)           // 75
#define OBJ_BLOCKS (NB * OBJ_CHUNKS)    // 1200
#define BT_BLOCKS  (NB * NT)            // 800
#define K2_BLOCKS  (OBJ_BLOCKS + BT_BLOCKS)  // 2000

// ws layout
// [0..15]   float acc[4]   (0=box 1=obj 2=cls)
// [16..19]  int   cnt
// [64 ..]   float val_part[NB*NCHUNK*NT]   (80000 B)
// [80064..] int   idx_part[NB*NCHUNK*NT]   (80000 B)

__device__ __forceinline__ float bce_logits(float x, float z) {
    return fmaxf(x, 0.0f) - x * z + log1pf(expf(-fabsf(x)));
}

// ------- K1: chunked argmax. block = (b, c). Reads each anchor ONCE. -------
__global__ __launch_bounds__(256) void argmax_part_kernel(
        const float4* __restrict__ pb,
        const float4* __restrict__ tb,
        float* __restrict__ val_part,
        int* __restrict__ idx_part,
        float* __restrict__ acc,
        int* __restrict__ cnt) {
    const int b = blockIdx.x / NCHUNK;
    const int c = blockIdx.x % NCHUNK;
    const int tid = threadIdx.x;

    if (blockIdx.x == 0) {
        if (tid < 4) acc[tid] = 0.0f;
        if (tid == 4) *cnt = 0;
    }

    __shared__ float4 sanc[A_BLK];
    __shared__ float4 stb[NT];
    __shared__ float  sarea[NT];
    __shared__ float  swval[4][TG];
    __shared__ int    swidx[4][TG];

    #pragma unroll
    for (int k = 0; k < 3; ++k) {
        int i = tid + k * 256;
        sanc[i] = pb[(size_t)b * NA + c * A_BLK + i];
    }
    if (tid < NT) {
        float4 t4 = tb[b * NT + tid];
        stb[tid] = t4;
        sarea[tid] = (t4.z - t4.x) * (t4.w - t4.y);
    }
    __syncthreads();

    const int wave = tid >> 6;
    const int lane = tid & 63;

    for (int p = 0; p < NPASS; ++p) {
        float best[TG];
        int   bidx[TG];
        #pragma unroll
        for (int g = 0; g < TG; ++g) { best[g] = -1.0f; bidx[g] = NA; }

        #pragma unroll
        for (int k = 0; k < 3; ++k) {
            const int a_loc = tid + k * 256;          // ascending in k -> first-idx kept
            float4 pq = sanc[a_loc];
            float area1 = (pq.z - pq.x) * (pq.w - pq.y);
            const int gidx = c * A_BLK + a_loc;
            #pragma unroll
            for (int g = 0; g < TG; ++g) {
                float4 t4 = stb[p * TG + g];
                float ix1 = fmaxf(pq.x, t4.x), iy1 = fmaxf(pq.y, t4.y);
                float ix2 = fminf(pq.z, t4.z), iy2 = fminf(pq.w, t4.w);
                float inter = fmaxf(ix2 - ix1, 0.0f) * fmaxf(iy2 - iy1, 0.0f);
                float iou = inter / (area1 + sarea[p * TG + g] - inter + F_EPS);
                if (iou > best[g]) { best[g] = iou; bidx[g] = gidx; }
            }
        }

        // wave butterfly argmax (max val, tie -> min idx)
        #pragma unroll
        for (int g = 0; g < TG; ++g) {
            float v = best[g];
            int   i = bidx[g];
            #pragma unroll
            for (int m = 1; m < 64; m <<= 1) {
                float ov = __shfl_xor(v, m);
                int   oi = __shfl_xor(i, m);
                if (ov > v || (ov == v && oi < i)) { v = ov; i = oi; }
            }
            if (lane == 0) { swval[wave][g] = v; swidx[wave][g] = i; }
        }
        __syncthreads();

        if (tid < TG) {
            float v = swval[0][tid];
            int   i = swidx[0][tid];
            #pragma unroll
            for (int w = 1; w < 4; ++w) {
                float ov = swval[w][tid];
                int   oi = swidx[w][tid];
                if (ov > v || (ov == v && oi < i)) { v = ov; i = oi; }
            }
            const int t = p * TG + tid;
            val_part[((size_t)b * NCHUNK + c) * NT + t] = v;
            idx_part[((size_t)b * NCHUNK + c) * NT + t] = i;
        }
        __syncthreads();
    }
}

// ------- K2 (fused): obj BCE + CIoU/cls + final combine -------
__global__ __launch_bounds__(256) void fused_loss_kernel(
        const float* __restrict__ pb,
        const float* __restrict__ pc,
        const float* __restrict__ pcls,
        const float* __restrict__ tb,
        const int* __restrict__ tl,
        const float* __restrict__ val_part,
        const int* __restrict__ idx_part,
        float* __restrict__ acc,
        int* __restrict__ cnt,
        float* __restrict__ out) {
    __shared__ float sred[256];
    __shared__ int   sbi[64];

    if (blockIdx.x < OBJ_BLOCKS) {
        // ---------------- objectness BCE ----------------
        const int b = blockIdx.x / OBJ_CHUNKS;
        const int a = (blockIdx.x % OBJ_CHUNKS) * 256 + threadIdx.x;

        if (threadIdx.x < NT) {
            const int t = threadIdx.x;
            float v = -2.0f; int i = NA;
            for (int c = 0; c < NCHUNK; ++c) {
                float ov = val_part[((size_t)b * NCHUNK + c) * NT + t];
                int   oi = idx_part[((size_t)b * NCHUNK + c) * NT + t];
                if (ov > v || (ov == v && oi < i)) { v = ov; i = oi; }
            }
            sbi[t] = i;
        }
        __syncthreads();

        float z = 0.0f;
        #pragma unroll
        for (int t = 0; t < NT; ++t)
            if (sbi[t] == a) z = 1.0f;

        float x = pc[(size_t)b * NA + a];
        sred[threadIdx.x] = bce_logits(x, z);
        __syncthreads();
        for (int s = 128; s > 0; s >>= 1) {
            if ((int)threadIdx.x < s) sred[threadIdx.x] += sred[threadIdx.x + s];
            __syncthreads();
        }
        if (threadIdx.x == 0) atomicAdd(acc + 1, sred[0]);
    } else {
        // ---------------- CIoU + class BCE ----------------
        const int bt = blockIdx.x - OBJ_BLOCKS;
        const int b  = bt / NT;
        const int t  = bt % NT;

        if (threadIdx.x == 0) {
            float v = -2.0f; int i = NA;
            for (int c = 0; c < NCHUNK; ++c) {
                float ov = val_part[((size_t)b * NCHUNK + c) * NT + t];
                int   oi = idx_part[((size_t)b * NCHUNK + c) * NT + t];
                if (ov > v || (ov == v && oi < i)) { v = ov; i = oi; }
            }
            sbi[0] = i;
        }
        __syncthreads();
        const int bi = sbi[0];

        float v = 0.0f;
        if (threadIdx.x < NC) {
            float x = pcls[((size_t)b * NA + bi) * NC + threadIdx.x];
            float z = (tl[bt] == (int)threadIdx.x) ? 1.0f : 0.0f;
            v = bce_logits(x, z);
        }
        sred[threadIdx.x] = v;
        __syncthreads();
        for (int s = 128; s > 0; s >>= 1) {
            if ((int)threadIdx.x < s) sred[threadIdx.x] += sred[threadIdx.x + s];
            __syncthreads();
        }

        if (threadIdx.x == 0) {
            atomicAdd(acc + 2, sred[0]);

            const float* p  = pb + ((size_t)b * NA + bi) * 4;
            const float* tg = tb + (size_t)bt * 4;
            float b1x1 = p[0],  b1y1 = p[1],  b1x2 = p[2],  b1y2 = p[3];
            float b2x1 = tg[0], b2y1 = tg[1], b2x2 = tg[2], b2y2 = tg[3];

            float area1 = (b1x2 - b1x1) * (b1y2 - b1y1);
            float area2 = (b2x2 - b2x1) * (b2y2 - b2y1);
            float iw = fmaxf(fminf(b1x2, b2x2) - fmaxf(b1x1, b2x1), 0.0f);
            float ih = fmaxf(fminf(b1y2, b2y2) - fmaxf(b1y1, b2y1), 0.0f);
            float inter = iw * ih;
            float iou = inter / (area1 + area2 - inter + F_EPS);

            float cdx = fmaxf(b1x2, b2x2) - fminf(b1x1, b2x1);
            float cdy = fmaxf(b1y2, b2y2) - fminf(b1y1, b2y1);
            float c_diag = cdx * cdx + cdy * cdy;

            float cx = (b1x1 + b1x2 - b2x1 - b2x2) * 0.5f;
            float cy = (b1y1 + b1y2 - b2y1 - b2y2) * 0.5f;
            float center_dist = cx * cx + cy * cy;

            float w1 = b1x2 - b1x1, h1 = b1y2 - b1y1;
            float w2 = b2x2 - b2x1, h2 = b2y2 - b2y1;
            float dat = atanf(w2 / h2) - atanf(w1 / h1);
            float vv = (float)(4.0 / (M_PI * M_PI)) * dat * dat;
            float alpha = vv / (1.0f - iou + vv + F_EPS);
            float ciou = iou - center_dist / c_diag - alpha * vv;
            atomicAdd(acc + 0, 1.0f - ciou);
        }
    }

    // ---------------- last block combines ----------------
    if (threadIdx.x == 0) {
        __threadfence();
        int old = atomicAdd(cnt, 1);
        if (old == K2_BLOCKS - 1) {
            __threadfence();
            float box = atomicAdd(acc + 0, 0.0f);
            float obj = atomicAdd(acc + 1, 0.0f);
            float cls = atomicAdd(acc + 2, 0.0f);
            out[0] = LAMBDA_COORD * box / (float)(NB * NT)
                   + obj / (float)(NB * NA)
                   + cls / (float)(NB * NT * NC);
        }
    }
}

extern "C" void kernel_launch(void* const* d_in, const int* in_sizes, int n_in,
                              void* d_out, int out_size, void* d_ws, size_t ws_size,
                              hipStream_t stream) {
    const float* pb   = (const float*)d_in[0];   // (B,A,4)
    const float* pc   = (const float*)d_in[1];   // (B,A,1)
    const float* pcls = (const float*)d_in[2];   // (B,A,C)
    const float* tb   = (const float*)d_in[3];   // (B,T,4)
    const int*   tl   = (const int*)d_in[4];     // (B,T)

    char* ws = (char*)d_ws;
    float* acc      = (float*)ws;                    // 16 B
    int*   cnt      = (int*)(ws + 16);
    float* val_part = (float*)(ws + 64);             // 80000 B
    int*   idx_part = (int*)(ws + 64 + 80000);       // 80000 B

    argmax_part_kernel<<<NB * NCHUNK, 256, 0, stream>>>(
        (const float4*)pb, (const float4*)tb, val_part, idx_part, acc, cnt);
    fused_loss_kernel<<<K2_BLOCKS, 256, 0, stream>>>(
        pb, pc, pcls, tb, tl, val_part, idx_part, acc, cnt, (float*)d_out);
}

// Round 4
// 96.040 us; speedup vs baseline: 1.2060x; 1.2060x over previous
//
#include <hip/hip_runtime.h>
#include <math.h>

#define NB 16
#define NA 19200
#define NT 50
#define NC 80
#define LAMBDA_COORD 5.0f
#define F_EPS 1e-6f

#define NCHUNK 25
#define A_BLK  768              // NA / NCHUNK; 3 anchors per thread at 256 threads
#define TG     10               // targets per pass
#define NPASS  (NT / TG)        // 5

#define OBJ_CHUNKS (NA / 256)           // 75
#define OBJ_BLOCKS (NB * OBJ_CHUNKS)    // 1200
#define BT_BLOCKS  (NB * NT)            // 800
#define K2_BLOCKS  (OBJ_BLOCKS + BT_BLOCKS)  // 2000

// ws layout
// [0..15]      float acc[4]   (0=box 1=obj 2=cls)
// [64 ..]      float val_part[NB*NCHUNK*NT]   (80000 B)
// [80064..]    int   idx_part[NB*NCHUNK*NT]   (80000 B)
// [160064..]   int   best_idx[NB*NT]          (3200 B)

__device__ __forceinline__ float bce_logits(float x, float z) {
    return fmaxf(x, 0.0f) - x * z + log1pf(expf(-fabsf(x)));
}

// ------- K1: chunked argmax partials. block = (b, c). Reads each anchor ONCE. -------
__global__ __launch_bounds__(256) void argmax_part_kernel(
        const float4* __restrict__ pb,
        const float4* __restrict__ tb,
        float* __restrict__ val_part,
        int* __restrict__ idx_part,
        float* __restrict__ acc) {
    const int b = blockIdx.x / NCHUNK;
    const int c = blockIdx.x % NCHUNK;
    const int tid = threadIdx.x;

    if (blockIdx.x == 0 && tid < 4) acc[tid] = 0.0f;   // visible to K3 via kernel boundary

    __shared__ float4 sanc[A_BLK];
    __shared__ float4 stb[NT];
    __shared__ float  sarea[NT];
    __shared__ float  swval[4][TG];
    __shared__ int    swidx[4][TG];

    #pragma unroll
    for (int k = 0; k < 3; ++k) {
        int i = tid + k * 256;
        sanc[i] = pb[(size_t)b * NA + c * A_BLK + i];
    }
    if (tid < NT) {
        float4 t4 = tb[b * NT + tid];
        stb[tid] = t4;
        sarea[tid] = (t4.z - t4.x) * (t4.w - t4.y);
    }
    __syncthreads();

    const int wave = tid >> 6;
    const int lane = tid & 63;

    for (int p = 0; p < NPASS; ++p) {
        float best[TG];
        int   bidx[TG];
        #pragma unroll
        for (int g = 0; g < TG; ++g) { best[g] = -1.0f; bidx[g] = NA; }

        #pragma unroll
        for (int k = 0; k < 3; ++k) {
            const int a_loc = tid + k * 256;          // ascending in k -> first-idx kept
            float4 pq = sanc[a_loc];
            float area1 = (pq.z - pq.x) * (pq.w - pq.y);
            const int gidx = c * A_BLK + a_loc;
            #pragma unroll
            for (int g = 0; g < TG; ++g) {
                float4 t4 = stb[p * TG + g];
                float ix1 = fmaxf(pq.x, t4.x), iy1 = fmaxf(pq.y, t4.y);
                float ix2 = fminf(pq.z, t4.z), iy2 = fminf(pq.w, t4.w);
                float inter = fmaxf(ix2 - ix1, 0.0f) * fmaxf(iy2 - iy1, 0.0f);
                float iou = inter / (area1 + sarea[p * TG + g] - inter + F_EPS);
                if (iou > best[g]) { best[g] = iou; bidx[g] = gidx; }
            }
        }

        // wave butterfly argmax (max val, tie -> min idx)
        #pragma unroll
        for (int g = 0; g < TG; ++g) {
            float v = best[g];
            int   i = bidx[g];
            #pragma unroll
            for (int m = 1; m < 64; m <<= 1) {
                float ov = __shfl_xor(v, m);
                int   oi = __shfl_xor(i, m);
                if (ov > v || (ov == v && oi < i)) { v = ov; i = oi; }
            }
            if (lane == 0) { swval[wave][g] = v; swidx[wave][g] = i; }
        }
        __syncthreads();

        if (tid < TG) {
            float v = swval[0][tid];
            int   i = swidx[0][tid];
            #pragma unroll
            for (int w = 1; w < 4; ++w) {
                float ov = swval[w][tid];
                int   oi = swidx[w][tid];
                if (ov > v || (ov == v && oi < i)) { v = ov; i = oi; }
            }
            const int t = p * TG + tid;
            val_part[((size_t)b * NCHUNK + c) * NT + t] = v;
            idx_part[((size_t)b * NCHUNK + c) * NT + t] = i;
        }
        __syncthreads();
    }
}

// ------- K1.5: merge chunk partials -> best_idx[NB*NT] -------
__global__ __launch_bounds__(64) void merge_kernel(
        const float* __restrict__ val_part,
        const int* __restrict__ idx_part,
        int* __restrict__ best_idx) {
    const int b = blockIdx.x;
    const int t = threadIdx.x;
    if (t >= NT) return;
    float v = -2.0f; int i = NA;
    for (int c = 0; c < NCHUNK; ++c) {
        float ov = val_part[((size_t)b * NCHUNK + c) * NT + t];
        int   oi = idx_part[((size_t)b * NCHUNK + c) * NT + t];
        if (ov > v || (ov == v && oi < i)) { v = ov; i = oi; }
    }
    best_idx[b * NT + t] = i;
}

// ------- K2 (fused): obj BCE (blocks [0,1200)) + CIoU/cls (blocks [1200,2000)) -------
__global__ __launch_bounds__(256) void fused_loss_kernel(
        const float* __restrict__ pb,
        const float* __restrict__ pc,
        const float* __restrict__ pcls,
        const float* __restrict__ tb,
        const int* __restrict__ tl,
        const int* __restrict__ best_idx,
        float* __restrict__ acc) {
    __shared__ float sred[256];

    if (blockIdx.x < OBJ_BLOCKS) {
        const int b = blockIdx.x / OBJ_CHUNKS;
        const int a = (blockIdx.x % OBJ_CHUNKS) * 256 + threadIdx.x;

        __shared__ int sbi[NT];
        if (threadIdx.x < NT) sbi[threadIdx.x] = best_idx[b * NT + threadIdx.x];
        __syncthreads();

        float z = 0.0f;
        #pragma unroll
        for (int t = 0; t < NT; ++t)
            if (sbi[t] == a) z = 1.0f;

        float x = pc[(size_t)b * NA + a];
        sred[threadIdx.x] = bce_logits(x, z);
        __syncthreads();
        for (int s = 128; s > 0; s >>= 1) {
            if ((int)threadIdx.x < s) sred[threadIdx.x] += sred[threadIdx.x + s];
            __syncthreads();
        }
        if (threadIdx.x == 0) atomicAdd(acc + 1, sred[0]);
    } else {
        const int bt = blockIdx.x - OBJ_BLOCKS;
        const int b  = bt / NT;
        const int bi = best_idx[bt];

        float v = 0.0f;
        if (threadIdx.x < NC) {
            float x = pcls[((size_t)b * NA + bi) * NC + threadIdx.x];
            float z = (tl[bt] == (int)threadIdx.x) ? 1.0f : 0.0f;
            v = bce_logits(x, z);
        }
        sred[threadIdx.x] = v;
        __syncthreads();
        for (int s = 128; s > 0; s >>= 1) {
            if ((int)threadIdx.x < s) sred[threadIdx.x] += sred[threadIdx.x + s];
            __syncthreads();
        }

        if (threadIdx.x == 0) {
            atomicAdd(acc + 2, sred[0]);

            const float* p  = pb + ((size_t)b * NA + bi) * 4;
            const float* tg = tb + (size_t)bt * 4;
            float b1x1 = p[0],  b1y1 = p[1],  b1x2 = p[2],  b1y2 = p[3];
            float b2x1 = tg[0], b2y1 = tg[1], b2x2 = tg[2], b2y2 = tg[3];

            float area1 = (b1x2 - b1x1) * (b1y2 - b1y1);
            float area2 = (b2x2 - b2x1) * (b2y2 - b2y1);
            float iw = fmaxf(fminf(b1x2, b2x2) - fmaxf(b1x1, b2x1), 0.0f);
            float ih = fmaxf(fminf(b1y2, b2y2) - fmaxf(b1y1, b2y1), 0.0f);
            float inter = iw * ih;
            float iou = inter / (area1 + area2 - inter + F_EPS);

            float cdx = fmaxf(b1x2, b2x2) - fminf(b1x1, b2x1);
            float cdy = fmaxf(b1y2, b2y2) - fminf(b1y1, b2y1);
            float c_diag = cdx * cdx + cdy * cdy;

            float cx = (b1x1 + b1x2 - b2x1 - b2x2) * 0.5f;
            float cy = (b1y1 + b1y2 - b2y1 - b2y2) * 0.5f;
            float center_dist = cx * cx + cy * cy;

            float w1 = b1x2 - b1x1, h1 = b1y2 - b1y1;
            float w2 = b2x2 - b2x1, h2 = b2y2 - b2y1;
            float dat = atanf(w2 / h2) - atanf(w1 / h1);
            float vv = (float)(4.0 / (M_PI * M_PI)) * dat * dat;
            float alpha = vv / (1.0f - iou + vv + F_EPS);
            float ciou = iou - center_dist / c_diag - alpha * vv;
            atomicAdd(acc + 0, 1.0f - ciou);
        }
    }
}

// ---------------- K3: combine ----------------
__global__ void final_kernel(const float* __restrict__ acc, float* __restrict__ out) {
    out[0] = LAMBDA_COORD * acc[0] / (float)(NB * NT)
           + acc[1] / (float)(NB * NA)
           + acc[2] / (float)(NB * NT * NC);
}

extern "C" void kernel_launch(void* const* d_in, const int* in_sizes, int n_in,
                              void* d_out, int out_size, void* d_ws, size_t ws_size,
                              hipStream_t stream) {
    const float* pb   = (const float*)d_in[0];   // (B,A,4)
    const float* pc   = (const float*)d_in[1];   // (B,A,1)
    const float* pcls = (const float*)d_in[2];   // (B,A,C)
    const float* tb   = (const float*)d_in[3];   // (B,T,4)
    const int*   tl   = (const int*)d_in[4];     // (B,T)

    char* ws = (char*)d_ws;
    float* acc      = (float*)ws;                       // 16 B
    float* val_part = (float*)(ws + 64);                // 80000 B
    int*   idx_part = (int*)(ws + 64 + 80000);          // 80000 B
    int*   best_idx = (int*)(ws + 64 + 160000);         // 3200 B

    argmax_part_kernel<<<NB * NCHUNK, 256, 0, stream>>>(
        (const float4*)pb, (const float4*)tb, val_part, idx_part, acc);
    merge_kernel<<<NB, 64, 0, stream>>>(val_part, idx_part, best_idx);
    fused_loss_kernel<<<K2_BLOCKS, 256, 0, stream>>>(
        pb, pc, pcls, tb, tl, best_idx, acc);
    final_kernel<<<1, 1, 0, stream>>>(acc, (float*)d_out);
}

// Round 5
// 70.516 us; speedup vs baseline: 1.6425x; 1.3619x over previous
//
#include <hip/hip_runtime.h>
#include <math.h>

#define NB 16
#define NA 19200
#define NT 50
#define NC 80
#define LAMBDA_COORD 5.0f
#define F_EPS 1e-6f

// K1: direct argmax. block = (b, group of TPG targets), all anchors per block.
#define TPG 5
#define NGRP (NT / TPG)          // 10
#define K1_BLOCKS (NB * NGRP)    // 160
#define K1_THREADS 1024
#define K1_WAVES (K1_THREADS / 64)

#define OBJ_CHUNKS (NA / 256)           // 75
#define OBJ_BLOCKS (NB * OBJ_CHUNKS)    // 1200
#define BT_BLOCKS  (NB * NT)            // 800
#define K2_BLOCKS  (OBJ_BLOCKS + BT_BLOCKS)  // 2000

// ws layout: [0..15] float acc[4] (0=box 1=obj 2=cls); [64..] int best_idx[NB*NT]

__device__ __forceinline__ float bce_logits(float x, float z) {
    return fmaxf(x, 0.0f) - x * z + log1pf(expf(-fabsf(x)));
}

// ------- K1: per-(b, target-group) argmax over ALL anchors; no partials -------
__global__ __launch_bounds__(1024) void argmax_direct_kernel(
        const float4* __restrict__ pb,
        const float4* __restrict__ tb,
        int* __restrict__ best_idx,
        float* __restrict__ acc) {
    const int b   = blockIdx.x / NGRP;
    const int g   = blockIdx.x % NGRP;
    const int tid = threadIdx.x;

    if (blockIdx.x == 0 && tid < 4) acc[tid] = 0.0f;   // stream-ordered: K2 sees zeros

    float4 t4[TPG];
    float  ta[TPG];
    #pragma unroll
    for (int i = 0; i < TPG; ++i) {
        t4[i] = tb[b * NT + g * TPG + i];
        ta[i] = (t4[i].z - t4[i].x) * (t4[i].w - t4[i].y);
    }

    float best[TPG];
    int   bidx[TPG];
    #pragma unroll
    for (int i = 0; i < TPG; ++i) { best[i] = -1.0f; bidx[i] = NA; }

    for (int a = tid; a < NA; a += K1_THREADS) {       // ascending -> first-idx ties kept
        float4 p = pb[(size_t)b * NA + a];
        float area1 = (p.z - p.x) * (p.w - p.y);
        #pragma unroll
        for (int i = 0; i < TPG; ++i) {
            float ix1 = fmaxf(p.x, t4[i].x), iy1 = fmaxf(p.y, t4[i].y);
            float ix2 = fminf(p.z, t4[i].z), iy2 = fminf(p.w, t4[i].w);
            float inter = fmaxf(ix2 - ix1, 0.0f) * fmaxf(iy2 - iy1, 0.0f);
            float iou = inter / (area1 + ta[i] - inter + F_EPS);
            if (iou > best[i]) { best[i] = iou; bidx[i] = a; }
        }
    }

    // per-wave butterfly (max val, tie -> min idx)
    const int wave = tid >> 6;
    const int lane = tid & 63;
    __shared__ float swv[K1_WAVES][TPG];
    __shared__ int   swi[K1_WAVES][TPG];
    #pragma unroll
    for (int i = 0; i < TPG; ++i) {
        float v = best[i];
        int   ix = bidx[i];
        #pragma unroll
        for (int m = 1; m < 64; m <<= 1) {
            float ov = __shfl_xor(v, m);
            int   oi = __shfl_xor(ix, m);
            if (ov > v || (ov == v && oi < ix)) { v = ov; ix = oi; }
        }
        if (lane == 0) { swv[wave][i] = v; swi[wave][i] = ix; }
    }
    __syncthreads();

    if (tid < TPG) {
        float v = swv[0][tid];
        int   ix = swi[0][tid];
        #pragma unroll
        for (int w = 1; w < K1_WAVES; ++w) {
            float ov = swv[w][tid];
            int   oi = swi[w][tid];
            if (ov > v || (ov == v && oi < ix)) { v = ov; ix = oi; }
        }
        best_idx[b * NT + g * TPG + tid] = ix;
    }
}

// ------- K2 (fused): obj BCE (blocks [0,1200)) + CIoU/cls (blocks [1200,2000)) -------
__global__ __launch_bounds__(256) void fused_loss_kernel(
        const float* __restrict__ pb,
        const float* __restrict__ pc,
        const float* __restrict__ pcls,
        const float* __restrict__ tb,
        const int* __restrict__ tl,
        const int* __restrict__ best_idx,
        float* __restrict__ acc) {
    __shared__ float sred[256];

    if (blockIdx.x < OBJ_BLOCKS) {
        const int b = blockIdx.x / OBJ_CHUNKS;
        const int a = (blockIdx.x % OBJ_CHUNKS) * 256 + threadIdx.x;

        __shared__ int sbi[NT];
        if (threadIdx.x < NT) sbi[threadIdx.x] = best_idx[b * NT + threadIdx.x];
        __syncthreads();

        float z = 0.0f;
        #pragma unroll
        for (int t = 0; t < NT; ++t)
            if (sbi[t] == a) z = 1.0f;

        float x = pc[(size_t)b * NA + a];
        sred[threadIdx.x] = bce_logits(x, z);
        __syncthreads();
        for (int s = 128; s > 0; s >>= 1) {
            if ((int)threadIdx.x < s) sred[threadIdx.x] += sred[threadIdx.x + s];
            __syncthreads();
        }
        if (threadIdx.x == 0) atomicAdd(acc + 1, sred[0]);
    } else {
        const int bt = blockIdx.x - OBJ_BLOCKS;
        const int b  = bt / NT;
        const int bi = best_idx[bt];

        float v = 0.0f;
        if (threadIdx.x < NC) {
            float x = pcls[((size_t)b * NA + bi) * NC + threadIdx.x];
            float z = (tl[bt] == (int)threadIdx.x) ? 1.0f : 0.0f;
            v = bce_logits(x, z);
        }
        sred[threadIdx.x] = v;
        __syncthreads();
        for (int s = 128; s > 0; s >>= 1) {
            if ((int)threadIdx.x < s) sred[threadIdx.x] += sred[threadIdx.x + s];
            __syncthreads();
        }

        if (threadIdx.x == 0) {
            atomicAdd(acc + 2, sred[0]);

            const float* p  = pb + ((size_t)b * NA + bi) * 4;
            const float* tg = tb + (size_t)bt * 4;
            float b1x1 = p[0],  b1y1 = p[1],  b1x2 = p[2],  b1y2 = p[3];
            float b2x1 = tg[0], b2y1 = tg[1], b2x2 = tg[2], b2y2 = tg[3];

            float area1 = (b1x2 - b1x1) * (b1y2 - b1y1);
            float area2 = (b2x2 - b2x1) * (b2y2 - b2y1);
            float iw = fmaxf(fminf(b1x2, b2x2) - fmaxf(b1x1, b2x1), 0.0f);
            float ih = fmaxf(fminf(b1y2, b2y2) - fmaxf(b1y1, b2y1), 0.0f);
            float inter = iw * ih;
            float iou = inter / (area1 + area2 - inter + F_EPS);

            float cdx = fmaxf(b1x2, b2x2) - fminf(b1x1, b2x1);
            float cdy = fmaxf(b1y2, b2y2) - fminf(b1y1, b2y1);
            float c_diag = cdx * cdx + cdy * cdy;

            float cx = (b1x1 + b1x2 - b2x1 - b2x2) * 0.5f;
            float cy = (b1y1 + b1y2 - b2y1 - b2y2) * 0.5f;
            float center_dist = cx * cx + cy * cy;

            float w1 = b1x2 - b1x1, h1 = b1y2 - b1y1;
            float w2 = b2x2 - b2x1, h2 = b2y2 - b2y1;
            float dat = atanf(w2 / h2) - atanf(w1 / h1);
            float vv = (float)(4.0 / (M_PI * M_PI)) * dat * dat;
            float alpha = vv / (1.0f - iou + vv + F_EPS);
            float ciou = iou - center_dist / c_diag - alpha * vv;
            atomicAdd(acc + 0, 1.0f - ciou);
        }
    }
}

// ---------------- K3: combine ----------------
__global__ void final_kernel(const float* __restrict__ acc, float* __restrict__ out) {
    out[0] = LAMBDA_COORD * acc[0] / (float)(NB * NT)
           + acc[1] / (float)(NB * NA)
           + acc[2] / (float)(NB * NT * NC);
}

extern "C" void kernel_launch(void* const* d_in, const int* in_sizes, int n_in,
                              void* d_out, int out_size, void* d_ws, size_t ws_size,
                              hipStream_t stream) {
    const float* pb   = (const float*)d_in[0];   // (B,A,4)
    const float* pc   = (const float*)d_in[1];   // (B,A,1)
    const float* pcls = (const float*)d_in[2];   // (B,A,C)
    const float* tb   = (const float*)d_in[3];   // (B,T,4)
    const int*   tl   = (const int*)d_in[4];     // (B,T)

    char* ws = (char*)d_ws;
    float* acc      = (float*)ws;            // 16 B
    int*   best_idx = (int*)(ws + 64);       // 3200 B

    argmax_direct_kernel<<<K1_BLOCKS, K1_THREADS, 0, stream>>>(
        (const float4*)pb, (const float4*)tb, best_idx, acc);
    fused_loss_kernel<<<K2_BLOCKS, 256, 0, stream>>>(
        pb, pc, pcls, tb, tl, best_idx, acc);
    final_kernel<<<1, 1, 0, stream>>>(acc, (float*)d_out);
}

// Round 6
// 39.174 us; speedup vs baseline: 2.9566x; 1.8001x over previous
//
#include <hip/hip_runtime.h>
#include <math.h>

#define NB 16
#define NA 19200
#define NT 50
#define NC 80
#define LAMBDA_COORD 5.0f
#define F_EPS 1e-6f

// K1: direct argmax. block = (b, group of TPG targets), all anchors per block.
#define TPG 5
#define NGRP (NT / TPG)          // 10
#define K1_BLOCKS (NB * NGRP)    // 160
#define K1_THREADS 1024
#define K1_WAVES (K1_THREADS / 64)

#define OBJ_CHUNKS (NA / 256)           // 75
#define OBJ_BLOCKS (NB * OBJ_CHUNKS)    // 1200
#define BT_BLOCKS  (NB * NT)            // 800
#define K2_BLOCKS  (OBJ_BLOCKS + BT_BLOCKS)  // 2000

// ws layout (all 64B aligned):
// [0     .. 4800)   float part_obj[1200]
// [4800  .. 8000)   float part_box[800]
// [8000  .. 11200)  float part_cls[800]
// [11200 .. 14400)  int   best_idx[800]

__device__ __forceinline__ float bce_logits(float x, float z) {
    return fmaxf(x, 0.0f) - x * z + log1pf(expf(-fabsf(x)));
}

// ------- K1: per-(b, target-group) argmax over ALL anchors; no partials -------
__global__ __launch_bounds__(1024) void argmax_direct_kernel(
        const float4* __restrict__ pb,
        const float4* __restrict__ tb,
        int* __restrict__ best_idx) {
    const int b   = blockIdx.x / NGRP;
    const int g   = blockIdx.x % NGRP;
    const int tid = threadIdx.x;

    float4 t4[TPG];
    float  ta[TPG];
    #pragma unroll
    for (int i = 0; i < TPG; ++i) {
        t4[i] = tb[b * NT + g * TPG + i];
        ta[i] = (t4[i].z - t4[i].x) * (t4[i].w - t4[i].y);
    }

    float best[TPG];
    int   bidx[TPG];
    #pragma unroll
    for (int i = 0; i < TPG; ++i) { best[i] = -1.0f; bidx[i] = NA; }

    for (int a = tid; a < NA; a += K1_THREADS) {       // ascending -> first-idx ties kept
        float4 p = pb[(size_t)b * NA + a];
        float area1 = (p.z - p.x) * (p.w - p.y);
        #pragma unroll
        for (int i = 0; i < TPG; ++i) {
            float ix1 = fmaxf(p.x, t4[i].x), iy1 = fmaxf(p.y, t4[i].y);
            float ix2 = fminf(p.z, t4[i].z), iy2 = fminf(p.w, t4[i].w);
            float inter = fmaxf(ix2 - ix1, 0.0f) * fmaxf(iy2 - iy1, 0.0f);
            float iou = inter / (area1 + ta[i] - inter + F_EPS);
            if (iou > best[i]) { best[i] = iou; bidx[i] = a; }
        }
    }

    // per-wave butterfly (max val, tie -> min idx)
    const int wave = tid >> 6;
    const int lane = tid & 63;
    __shared__ float swv[K1_WAVES][TPG];
    __shared__ int   swi[K1_WAVES][TPG];
    #pragma unroll
    for (int i = 0; i < TPG; ++i) {
        float v = best[i];
        int   ix = bidx[i];
        #pragma unroll
        for (int m = 1; m < 64; m <<= 1) {
            float ov = __shfl_xor(v, m);
            int   oi = __shfl_xor(ix, m);
            if (ov > v || (ov == v && oi < ix)) { v = ov; ix = oi; }
        }
        if (lane == 0) { swv[wave][i] = v; swi[wave][i] = ix; }
    }
    __syncthreads();

    if (tid < TPG) {
        float v = swv[0][tid];
        int   ix = swi[0][tid];
        #pragma unroll
        for (int w = 1; w < K1_WAVES; ++w) {
            float ov = swv[w][tid];
            int   oi = swi[w][tid];
            if (ov > v || (ov == v && oi < ix)) { v = ov; ix = oi; }
        }
        best_idx[b * NT + g * TPG + tid] = ix;
    }
}

// ------- K2 (fused): obj BCE + CIoU/cls; per-block partial STORES (no atomics) -------
__global__ __launch_bounds__(256) void fused_loss_kernel(
        const float* __restrict__ pb,
        const float* __restrict__ pc,
        const float* __restrict__ pcls,
        const float* __restrict__ tb,
        const int* __restrict__ tl,
        const int* __restrict__ best_idx,
        float* __restrict__ part_obj,
        float* __restrict__ part_box,
        float* __restrict__ part_cls) {
    __shared__ float sred[256];

    if (blockIdx.x < OBJ_BLOCKS) {
        const int b = blockIdx.x / OBJ_CHUNKS;
        const int a = (blockIdx.x % OBJ_CHUNKS) * 256 + threadIdx.x;

        __shared__ int sbi[NT];
        if (threadIdx.x < NT) sbi[threadIdx.x] = best_idx[b * NT + threadIdx.x];
        __syncthreads();

        float z = 0.0f;
        #pragma unroll
        for (int t = 0; t < NT; ++t)
            if (sbi[t] == a) z = 1.0f;

        float x = pc[(size_t)b * NA + a];
        sred[threadIdx.x] = bce_logits(x, z);
        __syncthreads();
        for (int s = 128; s > 0; s >>= 1) {
            if ((int)threadIdx.x < s) sred[threadIdx.x] += sred[threadIdx.x + s];
            __syncthreads();
        }
        if (threadIdx.x == 0) part_obj[blockIdx.x] = sred[0];
    } else {
        const int bt = blockIdx.x - OBJ_BLOCKS;
        const int b  = bt / NT;
        const int bi = best_idx[bt];

        float v = 0.0f;
        if (threadIdx.x < NC) {
            float x = pcls[((size_t)b * NA + bi) * NC + threadIdx.x];
            float z = (tl[bt] == (int)threadIdx.x) ? 1.0f : 0.0f;
            v = bce_logits(x, z);
        }
        sred[threadIdx.x] = v;
        __syncthreads();
        for (int s = 128; s > 0; s >>= 1) {
            if ((int)threadIdx.x < s) sred[threadIdx.x] += sred[threadIdx.x + s];
            __syncthreads();
        }

        if (threadIdx.x == 0) {
            part_cls[bt] = sred[0];

            const float* p  = pb + ((size_t)b * NA + bi) * 4;
            const float* tg = tb + (size_t)bt * 4;
            float b1x1 = p[0],  b1y1 = p[1],  b1x2 = p[2],  b1y2 = p[3];
            float b2x1 = tg[0], b2y1 = tg[1], b2x2 = tg[2], b2y2 = tg[3];

            float area1 = (b1x2 - b1x1) * (b1y2 - b1y1);
            float area2 = (b2x2 - b2x1) * (b2y2 - b2y1);
            float iw = fmaxf(fminf(b1x2, b2x2) - fmaxf(b1x1, b2x1), 0.0f);
            float ih = fmaxf(fminf(b1y2, b2y2) - fmaxf(b1y1, b2y1), 0.0f);
            float inter = iw * ih;
            float iou = inter / (area1 + area2 - inter + F_EPS);

            float cdx = fmaxf(b1x2, b2x2) - fminf(b1x1, b2x1);
            float cdy = fmaxf(b1y2, b2y2) - fminf(b1y1, b2y1);
            float c_diag = cdx * cdx + cdy * cdy;

            float cx = (b1x1 + b1x2 - b2x1 - b2x2) * 0.5f;
            float cy = (b1y1 + b1y2 - b2y1 - b2y2) * 0.5f;
            float center_dist = cx * cx + cy * cy;

            float w1 = b1x2 - b1x1, h1 = b1y2 - b1y1;
            float w2 = b2x2 - b2x1, h2 = b2y2 - b2y1;
            float dat = atanf(w2 / h2) - atanf(w1 / h1);
            float vv = (float)(4.0 / (M_PI * M_PI)) * dat * dat;
            float alpha = vv / (1.0f - iou + vv + F_EPS);
            float ciou = iou - center_dist / c_diag - alpha * vv;
            part_box[bt] = 1.0f - ciou;
        }
    }
}

// ---------------- K3: weighted sum of all partials ----------------
__global__ __launch_bounds__(256) void final_kernel(
        const float* __restrict__ part_obj,
        const float* __restrict__ part_box,
        const float* __restrict__ part_cls,
        float* __restrict__ out) {
    const float W_OBJ = 1.0f / (float)(NB * NA);
    const float W_BOX = LAMBDA_COORD / (float)(NB * NT);
    const float W_CLS = 1.0f / (float)(NB * NT * NC);

    float s = 0.0f;
    for (int i = threadIdx.x; i < OBJ_BLOCKS; i += 256) s += part_obj[i] * W_OBJ;
    for (int i = threadIdx.x; i < BT_BLOCKS; i += 256)
        s += part_box[i] * W_BOX + part_cls[i] * W_CLS;

    __shared__ float sred[256];
    sred[threadIdx.x] = s;
    __syncthreads();
    for (int st = 128; st > 0; st >>= 1) {
        if ((int)threadIdx.x < st) sred[threadIdx.x] += sred[threadIdx.x + st];
        __syncthreads();
    }
    if (threadIdx.x == 0) out[0] = sred[0];
}

extern "C" void kernel_launch(void* const* d_in, const int* in_sizes, int n_in,
                              void* d_out, int out_size, void* d_ws, size_t ws_size,
                              hipStream_t stream) {
    const float* pb   = (const float*)d_in[0];   // (B,A,4)
    const float* pc   = (const float*)d_in[1];   // (B,A,1)
    const float* pcls = (const float*)d_in[2];   // (B,A,C)
    const float* tb   = (const float*)d_in[3];   // (B,T,4)
    const int*   tl   = (const int*)d_in[4];     // (B,T)

    char* ws = (char*)d_ws;
    float* part_obj = (float*)ws;                 // 1200 floats
    float* part_box = (float*)(ws + 4800);        // 800 floats
    float* part_cls = (float*)(ws + 8000);        // 800 floats
    int*   best_idx = (int*)(ws + 11200);         // 800 ints

    argmax_direct_kernel<<<K1_BLOCKS, K1_THREADS, 0, stream>>>(
        (const float4*)pb, (const float4*)tb, best_idx);
    fused_loss_kernel<<<K2_BLOCKS, 256, 0, stream>>>(
        pb, pc, pcls, tb, tl, best_idx, part_obj, part_box, part_cls);
    final_kernel<<<1, 256, 0, stream>>>(part_obj, part_box, part_cls, (float*)d_out);
}